// Round 1
// 152.226 us; speedup vs baseline: 1.0882x; 1.0882x over previous
//
#include <hip/hip_runtime.h>
#include <math.h>

#define TT 2048
#define HH 128
#define ROWS 8
#define SP 132  // LDS row stride in floats (16B-aligned, bank-spread)

__device__ __forceinline__ float dot4(float4 a, float4 b) {
    return a.x * b.x + a.y * b.y + a.z * b.z + a.w * b.w;
}

// ---------------- prep: transpose/pack weights for coalesced column-major streaming ----
// win_p  [32][128]    float4: win_p[cg*128+col]        = w_in [col][4cg..4cg+3]
// wout_p [32][128]    float4: wout_p[cg*128+col]       = w_out[col][4cg..4cg+3]
// wcat   [L][32][512] float4: col<128 v, <256 q, <384 k, <512 o
// wff_p  [L][64][128] float4: wff_p[l][cg*128+col]     = w_ff[l][col][4cg..4cg+3]
__global__ __launch_bounds__(256) void prep_kernel(
        const float* __restrict__ w_in, const float* __restrict__ w_out,
        const float* __restrict__ w_v, const float* __restrict__ w_q,
        const float* __restrict__ w_k, const float* __restrict__ w_o,
        const float* __restrict__ w_ff,
        float4* __restrict__ win_p, float4* __restrict__ wout_p,
        float4* __restrict__ wcat, float4* __restrict__ wff_p) {
    int i = blockIdx.x * 256 + threadIdx.x;
    if (i < 4096) {
        int cg = i >> 7, col = i & 127;
        win_p[i] = ((const float4*)w_in)[col * 32 + cg];
    } else if (i < 8192) {
        int j = i - 4096, cg = j >> 7, col = j & 127;
        wout_p[j] = ((const float4*)w_out)[col * 32 + cg];
    } else if (i < 40960) {
        int j = i - 8192;
        int l = j >> 14, r = j & 16383, cg = r >> 9, col = r & 511;
        int sel = col >> 7, cm = col & 127;
        const float* s = (sel == 0 ? w_v : sel == 1 ? w_q : sel == 2 ? w_k : w_o) + l * HH * HH;
        wcat[j] = ((const float4*)s)[cm * 32 + cg];
    } else {
        int j = i - 40960;
        int l = j >> 13, r = j & 8191, cg = r >> 7, col = r & 127;
        const float* s = w_ff + l * HH * 256;
        wff_p[j] = ((const float4*)s)[col * 64 + cg];
    }
}

// ---- attention: wave wv owns row t0+wv. lane covers dims {2l,2l+1}.
// Software-pipelined: prefetch tp-1 before the reduce. Break on g==0 (== start, since
// mask forces g=0 at starts; if g==0 for any reason, earlier terms have decay 0 anyway).
__device__ __forceinline__ void attn_row(int t0,
        const float* __restrict__ kb, const float* __restrict__ vb,
        const float* __restrict__ qb, const float* __restrict__ ob,
        const float* __restrict__ g, const float* __restrict__ iexp,
        float* __restrict__ hs) {
    int tid = threadIdx.x;
    int wv = tid >> 6, lane = tid & 63;
    int t = t0 + wv;
    float2 q2 = *(const float2*)(qb + t * HH + 2 * lane);
    float2 o2 = *(const float2*)(ob + t * HH + 2 * lane);
    int tp = t;
    float2 k2 = *(const float2*)(kb + tp * HH + 2 * lane);
    float2 v2 = *(const float2*)(vb + tp * HH + 2 * lane);
    float ie = iexp[tp], gv = g[tp];
    float nx = 0.f, ny = 0.f, dsum = 0.f, decay = 1.f;
    while (true) {
        bool cont = (tp > 0) && (gv != 0.f);
        float2 k2n = {0.f, 0.f}, v2n = {0.f, 0.f};
        float ien = 0.f, gvn = 0.f;
        if (cont) {  // prefetch next step; overlaps the reduce below
            k2n = *(const float2*)(kb + (tp - 1) * HH + 2 * lane);
            v2n = *(const float2*)(vb + (tp - 1) * HH + 2 * lane);
            ien = iexp[tp - 1]; gvn = g[tp - 1];
        }
        float p = k2.x * q2.x + k2.y * q2.y;
#pragma unroll
        for (int off = 1; off <= 32; off <<= 1) p += __shfl_xor(p, off, 64);
        float coeff = decay * ie * p;
        nx += coeff * v2.x; ny += coeff * v2.y; dsum += coeff;
        if (!cont) break;
        decay *= gv;
        tp--; k2 = k2n; v2 = v2n; ie = ien; gv = gvn;
    }
    float inv = 1.f / fmaxf(fabsf(dsum), 1.f);
    *(float2*)(hs + wv * SP + 2 * lane) = make_float2(o2.x * nx * inv, o2.y * ny * inv);
}

// ---- f/i scalar gates: wave wv handles row wv (cheap wave-reduce).
__device__ __forceinline__ void proj_fi(int t0, const float* __restrict__ xls,
        const float* __restrict__ w_f, const float* __restrict__ b_f,
        const float* __restrict__ w_i, const float* __restrict__ b_i,
        const int* __restrict__ start, float* __restrict__ g, float* __restrict__ iexp) {
    int tid = threadIdx.x;
    int wv = tid >> 6, lane = tid & 63;
    const float* x = xls + wv * SP + 2 * lane;
    float pf = x[0] * w_f[2 * lane] + x[1] * w_f[2 * lane + 1];
    float pi = x[0] * w_i[2 * lane] + x[1] * w_i[2 * lane + 1];
#pragma unroll
    for (int off = 1; off <= 32; off <<= 1) {
        pf += __shfl_xor(pf, off, 64);
        pi += __shfl_xor(pi, off, 64);
    }
    if (lane == 0) {
        int t = t0 + wv;
        g[t] = start[t] ? 0.f : 1.f / (1.f + expf(-(pf + b_f[0])));
        iexp[t] = expf(pi + b_i[0]);
    }
}

// ---- 4 projections, column-major: thread = output col (512 cols = v|q|k|o).
// Weight loads are lane-consecutive float4 (coalesced 1KB/wave); x is an LDS broadcast.
__device__ __forceinline__ void proj_block(int t0, const float* __restrict__ xls,
        const float4* __restrict__ wcat,
        const float* __restrict__ b_v, const float* __restrict__ b_q,
        const float* __restrict__ b_k, const float* __restrict__ b_o,
        float* __restrict__ vb, float* __restrict__ qb,
        float* __restrict__ kb, float* __restrict__ ob) {
    int tid = threadIdx.x;
    int col = tid, mat = tid >> 7, cm = tid & 127;  // mat is wave-uniform
    float acc[8] = {0.f, 0.f, 0.f, 0.f, 0.f, 0.f, 0.f, 0.f};
#pragma unroll 8
    for (int cg = 0; cg < 32; ++cg) {
        float4 w4 = wcat[cg * 512 + col];
#pragma unroll
        for (int r = 0; r < 8; ++r) {
            float4 x4 = *(const float4*)(xls + r * SP + 4 * cg);
            acc[r] += dot4(x4, w4);
        }
    }
    const float ks = 0.088388347648318447f;  // 1/sqrt(128)
    const float* bsel = mat == 0 ? b_v : mat == 1 ? b_q : mat == 2 ? b_k : b_o;
    float* dst = mat == 0 ? vb : mat == 1 ? qb : mat == 2 ? kb : ob;
    float bb = bsel[cm];
#pragma unroll
    for (int r = 0; r < 8; ++r) {
        float a = acc[r];
        if (mat == 2) a *= ks;
        a += bb;
        if (mat == 3) a = 1.f / (1.f + expf(-a));
        dst[(t0 + r) * HH + cm] = a;
    }
}

// ---- ff: z = lrelu([h, e] @ w_ff.T + b_ff); thread = (col, row-pair).
__device__ __forceinline__ void ff_block(const float* __restrict__ hsb,
        const float* __restrict__ esb, const float4* __restrict__ wff,
        const float* __restrict__ b_ff, float* __restrict__ zs) {
    int tid = threadIdx.x;
    int col = tid & 127, rg = tid >> 7;
    int r0 = 2 * rg, r1 = r0 + 1;
    float a0 = 0.f, a1 = 0.f;
#pragma unroll 8
    for (int cg = 0; cg < 32; ++cg) {
        float4 w4 = wff[cg * 128 + col];
        a0 += dot4(*(const float4*)(hsb + r0 * SP + 4 * cg), w4);
        a1 += dot4(*(const float4*)(hsb + r1 * SP + 4 * cg), w4);
    }
#pragma unroll 8
    for (int cg = 32; cg < 64; ++cg) {
        float4 w4 = wff[cg * 128 + col];
        int c = 4 * (cg - 32);
        a0 += dot4(*(const float4*)(esb + r0 * SP + c), w4);
        a1 += dot4(*(const float4*)(esb + r1 * SP + c), w4);
    }
    float bb = b_ff[col];
    a0 += bb; a1 += bb;
    a0 = a0 > 0.f ? a0 : 0.01f * a0;
    a1 = a1 > 0.f ? a1 : 0.01f * a1;
    zs[r0 * SP + col] = a0;
    zs[r1 * SP + col] = a1;
}

// ---- generic 128->128 dense (e-proj in k1, out-proj in k3), column-major.
__device__ __forceinline__ void dense128(int t0, const float* __restrict__ xls,
        const float4* __restrict__ Wp, const float* __restrict__ b,
        float* __restrict__ yg, float* __restrict__ ys) {
    int tid = threadIdx.x;
    int col = tid & 127, rg = tid >> 7;
    int r0 = 2 * rg, r1 = r0 + 1;
    float a0 = 0.f, a1 = 0.f;
#pragma unroll 8
    for (int cg = 0; cg < 32; ++cg) {
        float4 w4 = Wp[cg * 128 + col];
        a0 += dot4(*(const float4*)(xls + r0 * SP + 4 * cg), w4);
        a1 += dot4(*(const float4*)(xls + r1 * SP + 4 * cg), w4);
    }
    float bb = b[col];
    a0 += bb; a1 += bb;
    yg[(t0 + r0) * HH + col] = a0;
    yg[(t0 + r1) * HH + col] = a1;
    if (ys) {
        ys[r0 * SP + col] = a0;
        ys[r1 * SP + col] = a1;
    }
}

// ---------------- K1: e = emb @ w_in.T + b_in; layer-0 projections ----------------
__global__ __launch_bounds__(512, 2) void k1_kernel(
        const float* __restrict__ emb, const int* __restrict__ start,
        const float4* __restrict__ win_p, const float* __restrict__ b_in,
        const float4* __restrict__ wcat0,
        const float* __restrict__ b_v, const float* __restrict__ b_q,
        const float* __restrict__ b_k, const float* __restrict__ b_o,
        const float* __restrict__ w_f, const float* __restrict__ b_f,
        const float* __restrict__ w_i, const float* __restrict__ b_i,
        float* __restrict__ e, float* __restrict__ kb, float* __restrict__ vb,
        float* __restrict__ qb, float* __restrict__ ob,
        float* __restrict__ g, float* __restrict__ iexp) {
    __shared__ float xs[ROWS * SP];
    __shared__ float es[ROWS * SP];
    int tid = threadIdx.x;
    int t0 = blockIdx.x * ROWS;
    int wv = tid >> 6, lane = tid & 63;
    *(float2*)(xs + wv * SP + 2 * lane) = *(const float2*)(emb + (t0 + wv) * HH + 2 * lane);
    __syncthreads();
    dense128(t0, xs, win_p, b_in, e, es);
    __syncthreads();
    proj_block(t0, es, wcat0, b_v, b_q, b_k, b_o, vb, qb, kb, ob);
    proj_fi(t0, es, w_f, b_f, w_i, b_i, start, g, iexp);
}

// ---------------- K2: attn0 + ff0 + layer-1 projections ----------------
__global__ __launch_bounds__(512, 2) void k2_kernel(
        const int* __restrict__ start, const float* __restrict__ e,
        const float* __restrict__ k0, const float* __restrict__ v0,
        const float* __restrict__ q0, const float* __restrict__ o0,
        const float* __restrict__ g0, const float* __restrict__ i0,
        const float4* __restrict__ wff0, const float* __restrict__ b_ff,
        const float4* __restrict__ wcat1,
        const float* __restrict__ b_v, const float* __restrict__ b_q,
        const float* __restrict__ b_k, const float* __restrict__ b_o,
        const float* __restrict__ w_f, const float* __restrict__ b_f,
        const float* __restrict__ w_i, const float* __restrict__ b_i,
        float* __restrict__ kb, float* __restrict__ vb,
        float* __restrict__ qb, float* __restrict__ ob,
        float* __restrict__ g, float* __restrict__ iexp) {
    __shared__ float es[ROWS * SP];
    __shared__ float hs[ROWS * SP];
    __shared__ float zs[ROWS * SP];
    int tid = threadIdx.x;
    int t0 = blockIdx.x * ROWS;
    int wv = tid >> 6, lane = tid & 63;
    float2 ev = *(const float2*)(e + (t0 + wv) * HH + 2 * lane);
    attn_row(t0, k0, v0, q0, o0, g0, i0, hs);
    *(float2*)(es + wv * SP + 2 * lane) = ev;
    __syncthreads();
    ff_block(hs, es, wff0, b_ff, zs);
    __syncthreads();
    proj_block(t0, zs, wcat1, b_v, b_q, b_k, b_o, vb, qb, kb, ob);
    proj_fi(t0, zs, w_f, b_f, w_i, b_i, start, g, iexp);
}

// ---------------- K3: attn1 + ff1 + final dense ----------------
__global__ __launch_bounds__(512, 2) void k3_kernel(
        const float* __restrict__ e,
        const float* __restrict__ k1, const float* __restrict__ v1,
        const float* __restrict__ q1, const float* __restrict__ o1,
        const float* __restrict__ g1, const float* __restrict__ i1,
        const float4* __restrict__ wff1, const float* __restrict__ b_ff,
        const float4* __restrict__ wout_p, const float* __restrict__ b_out,
        float* __restrict__ out) {
    __shared__ float es[ROWS * SP];
    __shared__ float hs[ROWS * SP];
    __shared__ float zs[ROWS * SP];
    int tid = threadIdx.x;
    int t0 = blockIdx.x * ROWS;
    int wv = tid >> 6, lane = tid & 63;
    float2 ev = *(const float2*)(e + (t0 + wv) * HH + 2 * lane);
    attn_row(t0, k1, v1, q1, o1, g1, i1, hs);
    *(float2*)(es + wv * SP + 2 * lane) = ev;
    __syncthreads();
    ff_block(hs, es, wff1, b_ff, zs);
    __syncthreads();
    dense128(t0, zs, wout_p, b_out, out, (float*)0);
}

extern "C" void kernel_launch(void* const* d_in, const int* in_sizes, int n_in,
                              void* d_out, int out_size, void* d_ws, size_t ws_size,
                              hipStream_t stream) {
    const float* emb   = (const float*)d_in[0];
    const int*   start = (const int*)  d_in[1];
    const float* w_in  = (const float*)d_in[2];
    const float* b_in  = (const float*)d_in[3];
    const float* w_out = (const float*)d_in[4];
    const float* b_out = (const float*)d_in[5];
    const float* w_f   = (const float*)d_in[6];
    const float* b_f   = (const float*)d_in[7];
    const float* w_i   = (const float*)d_in[8];
    const float* b_i   = (const float*)d_in[9];
    const float* w_v   = (const float*)d_in[10];
    const float* b_v   = (const float*)d_in[11];
    const float* w_q   = (const float*)d_in[12];
    const float* b_q   = (const float*)d_in[13];
    const float* w_k   = (const float*)d_in[14];
    const float* b_k   = (const float*)d_in[15];
    const float* w_o   = (const float*)d_in[16];
    const float* b_o   = (const float*)d_in[17];
    const float* w_ff  = (const float*)d_in[18];
    const float* b_ff  = (const float*)d_in[19];
    float* out = (float*)d_out;

    float* ws = (float*)d_ws;
    float* e   = ws; ws += TT * HH;
    float* k0b = ws; ws += TT * HH;
    float* v0b = ws; ws += TT * HH;
    float* q0b = ws; ws += TT * HH;
    float* o0b = ws; ws += TT * HH;
    float* k1b = ws; ws += TT * HH;
    float* v1b = ws; ws += TT * HH;
    float* q1b = ws; ws += TT * HH;
    float* o1b = ws; ws += TT * HH;
    float* g0  = ws; ws += TT;
    float* i0  = ws; ws += TT;
    float* g1  = ws; ws += TT;
    float* i1  = ws; ws += TT;
    float4* win_p  = (float4*)ws; ws += 16384;   // 4096 float4
    float4* wout_p = (float4*)ws; ws += 16384;   // 4096 float4
    float4* wcat   = (float4*)ws; ws += 131072;  // 32768 float4 (2 layers)
    float4* wff_p  = (float4*)ws; ws += 65536;   // 16384 float4 (2 layers)

    dim3 grid(TT / ROWS), block(512);
    prep_kernel<<<dim3(224), dim3(256), 0, stream>>>(
        w_in, w_out, w_v, w_q, w_k, w_o, w_ff, win_p, wout_p, wcat, wff_p);
    k1_kernel<<<grid, block, 0, stream>>>(
        emb, start, win_p, b_in, wcat,
        b_v, b_q, b_k, b_o, w_f, b_f, w_i, b_i,
        e, k0b, v0b, q0b, o0b, g0, i0);
    k2_kernel<<<grid, block, 0, stream>>>(
        start, e, k0b, v0b, q0b, o0b, g0, i0,
        wff_p, b_ff,
        wcat + 16384,
        b_v + HH, b_q + HH, b_k + HH, b_o + HH,
        w_f + HH, b_f + 1, w_i + HH, b_i + 1,
        k1b, v1b, q1b, o1b, g1, i1);
    k3_kernel<<<grid, block, 0, stream>>>(
        e, k1b, v1b, q1b, o1b, g1, i1,
        wff_p + 8192, b_ff + HH, wout_p, b_out, out);
}